// Round 4
// baseline (204.067 us; speedup 1.0000x reference)
//
#include <hip/hip_runtime.h>
#include <math.h>

// Problem: B=4, L=1024, C1=1024, C2=1024, K=32, K_IN=32, g=256.
// N = B*L = 4096 rows. All f32.
//
// ws layout (floats):
//   wT      [1024*1024]            off 0
//   linT    [2][256*1024]          off 1048576
//   xc      [2][4096*256]          off 1572864
//   partials[256][4][256]          off 3670016
//   sc      [2][2][256]            off 3932160
//   logits  [8192][1024]           off 3933184
//   tidx    [8192][32] (u32)       off 12321792
//   tval    [8192][32]             off 12583936
// total ~12.85M floats = 51.4 MB

__device__ __forceinline__ unsigned int ford(float f) {
    unsigned int b = __float_as_uint(f);
    return (b & 0x80000000u) ? ~b : (b | 0x80000000u);
}

// ---------------- generic 32x32 tiled transpose: in (R,C) -> out (C,R) -------
__global__ __launch_bounds__(256) void transpose_k(const float* __restrict__ in,
                                                   float* __restrict__ out,
                                                   int R, int C) {
    __shared__ float tile[32][33];
    int c0 = blockIdx.x * 32, r0 = blockIdx.y * 32;
    int tx = threadIdx.x, ty = threadIdx.y;  // block (32,8)
#pragma unroll
    for (int i = 0; i < 32; i += 8)
        tile[ty + i][tx] = in[(size_t)(r0 + ty + i) * C + c0 + tx];
    __syncthreads();
#pragma unroll
    for (int i = 0; i < 32; i += 8)
        out[(size_t)(c0 + ty + i) * R + r0 + tx] = tile[tx][ty + i];
}

// ---------------- grouped 1x1 conv (4->1) for both branches + partial stats --
__global__ __launch_bounds__(256) void conv_stats_k(
    const float* __restrict__ x,
    const float* __restrict__ so_w, const float* __restrict__ so_b,
    const float* __restrict__ si_w, const float* __restrict__ si_b,
    float* __restrict__ xc, float* __restrict__ partials) {
    int g = threadIdx.x;          // channel 0..255
    int n0 = blockIdx.x * 16;     // 256 blocks x 16 rows
    float4 wo = ((const float4*)so_w)[g]; float bo = so_b[g];
    float4 wi = ((const float4*)si_w)[g]; float bi = si_b[g];
    float so_s = 0.f, so_q = 0.f, si_s = 0.f, si_q = 0.f;
#pragma unroll
    for (int r = 0; r < 16; ++r) {
        int n = n0 + r;
        float4 xv = ((const float4*)x)[n * 256 + g];
        float co = fmaf(xv.x, wo.x, fmaf(xv.y, wo.y, fmaf(xv.z, wo.z, fmaf(xv.w, wo.w, bo))));
        float ci = fmaf(xv.x, wi.x, fmaf(xv.y, wi.y, fmaf(xv.z, wi.z, fmaf(xv.w, wi.w, bi))));
        xc[n * 256 + g] = co;
        xc[1048576 + n * 256 + g] = ci;
        so_s += co; so_q += co * co;
        si_s += ci; si_q += ci * ci;
    }
    int b = blockIdx.x;
    partials[(b * 4 + 0) * 256 + g] = so_s;
    partials[(b * 4 + 1) * 256 + g] = so_q;
    partials[(b * 4 + 2) * 256 + g] = si_s;
    partials[(b * 4 + 3) * 256 + g] = si_q;
}

// ---------------- finalize BN stats -> per-channel scale/shift ---------------
__global__ __launch_bounds__(256) void stats_k(
    const float* __restrict__ partials,
    const float* __restrict__ g_so, const float* __restrict__ b_so,
    const float* __restrict__ g_si, const float* __restrict__ b_si,
    float* __restrict__ sc) {
    int g = threadIdx.x;
    int br = blockIdx.x;  // 0 = so, 1 = si
    float s = 0.f, q = 0.f;
    for (int b = 0; b < 256; ++b) {
        s += partials[(b * 4 + br * 2 + 0) * 256 + g];
        q += partials[(b * 4 + br * 2 + 1) * 256 + g];
    }
    float mean = s * (1.f / 4096.f);
    float var  = q * (1.f / 4096.f) - mean * mean;  // biased, matches ref
    float rstd = rsqrtf(var + 1e-5f);
    float gm = br ? g_si[g] : g_so[g];
    float bt = br ? b_si[g] : b_so[g];
    float scale = gm * rstd;
    sc[br * 512 + g]       = scale;
    sc[br * 512 + 256 + g] = fmaf(-mean, scale, bt);
}

// ---------------- BN+GELU fused + (4096x256)@(256x1024) f32 GEMM -------------
// Per-CU LDS issue is the scarce resource (1 LDS unit serves 4 SIMDs), so the
// per-thread tile is 8 rows x 8 cols: per k only 2 ds_read_b128 (broadcast
// rows) + 2 global dwordx4 (cols, L2-resident) feed 64 FMAs.
//   DS:  2048 waves x 256k x 2 x ~12cy /256CU ~= 20us
//   VALU: 33.5M fma-insts x 2cy /1024 SIMD    ~= 27us  <- limiter
// Block = 16 rows x 1024 cols (wave = row-half x col-half); grid 256x2.
__global__ __launch_bounds__(256, 2) void logits_k(
    const float* __restrict__ xc, const float* __restrict__ sc,
    const float* __restrict__ linT,
    const float* __restrict__ so_lb, const float* __restrict__ si_lb,
    float* __restrict__ logits) {
    int t = threadIdx.x;
    int n0 = blockIdx.x * 16;
    int br = blockIdx.y;
    int wave = t >> 6, lane = t & 63;
    int rh = wave >> 1;                 // rows 8*rh .. 8*rh+7
    int ch = wave & 1;                  // col half
    int col0 = ch * 512 + lane * 4;     // cols col0..+3 and col0+256..+259

    __shared__ float xaT[32][16];       // [k within chunk][row]

    const float* xcb = xc + (size_t)br * 1048576;
    const float* lt  = linT + (size_t)br * 262144;

    int skk = t >> 3;                   // staging k 0..31
    int sr2 = (t & 7) * 2;              // staging rows sr2, sr2+1

    float4 accA[2][4];                  // [row-quad][col i] over rows (float4)
    float4 accB[2][4];
#pragma unroll
    for (int a = 0; a < 2; ++a)
#pragma unroll
        for (int i = 0; i < 4; ++i) {
            accA[a][i] = make_float4(0.f, 0.f, 0.f, 0.f);
            accB[a][i] = make_float4(0.f, 0.f, 0.f, 0.f);
        }

    for (int kc = 0; kc < 8; ++kc) {
        int k0 = kc * 32;
        // ---- stage xa^T chunk (BN + exact GELU fused), 2 rows per thread ----
        float c0 = xcb[(n0 + sr2 + 0) * 256 + k0 + skk];
        float c1 = xcb[(n0 + sr2 + 1) * 256 + k0 + skk];
        float scl = sc[br * 512 + k0 + skk];
        float shf = sc[br * 512 + 256 + k0 + skk];
        float z0 = fmaf(c0, scl, shf);
        float z1 = fmaf(c1, scl, shf);
        float2 gw;
        gw.x = 0.5f * z0 * (1.f + erff(z0 * 0.70710678f));
        gw.y = 0.5f * z1 * (1.f + erff(z1 * 0.70710678f));
        __syncthreads();  // previous chunk's reads done
        *(float2*)&xaT[skk][sr2] = gw;
        __syncthreads();  // chunk staged

#pragma unroll 4
        for (int kk = 0; kk < 32; ++kk) {
            const float* ltk = lt + (size_t)(k0 + kk) * 1024;
            float4 wA = *(const float4*)&ltk[col0];
            float4 wB = *(const float4*)&ltk[col0 + 256];
            float4 a0 = *(const float4*)&xaT[kk][8 * rh];      // uniform bcast
            float4 a1 = *(const float4*)&xaT[kk][8 * rh + 4];
#pragma unroll
            for (int i = 0; i < 4; ++i) {
                float wa = (&wA.x)[i], wb = (&wB.x)[i];
                accA[0][i].x = fmaf(a0.x, wa, accA[0][i].x);
                accA[0][i].y = fmaf(a0.y, wa, accA[0][i].y);
                accA[0][i].z = fmaf(a0.z, wa, accA[0][i].z);
                accA[0][i].w = fmaf(a0.w, wa, accA[0][i].w);
                accA[1][i].x = fmaf(a1.x, wa, accA[1][i].x);
                accA[1][i].y = fmaf(a1.y, wa, accA[1][i].y);
                accA[1][i].z = fmaf(a1.z, wa, accA[1][i].z);
                accA[1][i].w = fmaf(a1.w, wa, accA[1][i].w);
                accB[0][i].x = fmaf(a0.x, wb, accB[0][i].x);
                accB[0][i].y = fmaf(a0.y, wb, accB[0][i].y);
                accB[0][i].z = fmaf(a0.z, wb, accB[0][i].z);
                accB[0][i].w = fmaf(a0.w, wb, accB[0][i].w);
                accB[1][i].x = fmaf(a1.x, wb, accB[1][i].x);
                accB[1][i].y = fmaf(a1.y, wb, accB[1][i].y);
                accB[1][i].z = fmaf(a1.z, wb, accB[1][i].z);
                accB[1][i].w = fmaf(a1.w, wb, accB[1][i].w);
            }
        }
    }

    const float* lb = br ? si_lb : so_lb;
    float4 lbA = *(const float4*)&lb[col0];
    float4 lbB = *(const float4*)&lb[col0 + 256];
    float* lg = logits + ((size_t)br * 4096 + n0) * 1024;
#pragma unroll
    for (int a = 0; a < 2; ++a)
#pragma unroll
        for (int ri = 0; ri < 4; ++ri) {
            int row = 8 * rh + 4 * a + ri;
            float4 vA, vB;
            vA.x = (&accA[a][0].x)[ri] + lbA.x;
            vA.y = (&accA[a][1].x)[ri] + lbA.y;
            vA.z = (&accA[a][2].x)[ri] + lbA.z;
            vA.w = (&accA[a][3].x)[ri] + lbA.w;
            vB.x = (&accB[a][0].x)[ri] + lbB.x;
            vB.y = (&accB[a][1].x)[ri] + lbB.y;
            vB.z = (&accB[a][2].x)[ri] + lbB.z;
            vB.w = (&accB[a][3].x)[ri] + lbB.w;
            *(float4*)&lg[(size_t)row * 1024 + col0]       = vA;
            *(float4*)&lg[(size_t)row * 1024 + col0 + 256] = vB;
        }
}

// ---------------- softmax stats + exact top-32 per row-branch ----------------
// One wave per row-branch. 3-level radix-histogram select on the orderable key
// (8 bits/level, 24 bits total), then a tiny serial argmax over the boundary
// set with full 64-bit (key, ~idx) ordering -> selected SET exactly matches
// jax.lax.top_k (ties -> lowest index). Output order is arbitrary (consumer is
// order-invariant).
__global__ __launch_bounds__(256) void topk_k(const float* __restrict__ logits,
                                              unsigned int* __restrict__ tidx,
                                              float* __restrict__ tval) {
    __shared__ unsigned int hist[4][256];
    __shared__ unsigned int wcnt[4];
    int wave = threadIdx.x >> 6, lane = threadIdx.x & 63;
    int rb = blockIdx.x * 4 + wave;  // 0..8191
    unsigned int* h = hist[wave];

    const float4* lg = (const float4*)(logits + (size_t)rb * 1024);
    float v[16];
#pragma unroll
    for (int q = 0; q < 4; ++q) {
        float4 f = lg[q * 64 + lane];
        v[q * 4 + 0] = f.x; v[q * 4 + 1] = f.y;
        v[q * 4 + 2] = f.z; v[q * 4 + 3] = f.w;
    }
    // row max
    float rmax = v[0];
#pragma unroll
    for (int i = 1; i < 16; ++i) rmax = fmaxf(rmax, v[i]);
#pragma unroll
    for (int s = 32; s; s >>= 1) rmax = fmaxf(rmax, __shfl_xor(rmax, s));
    // softmax denominator
    float rsum = 0.f;
#pragma unroll
    for (int i = 0; i < 16; ++i) rsum += __expf(v[i] - rmax);
#pragma unroll
    for (int s = 32; s; s >>= 1) rsum += __shfl_xor(rsum, s);

    unsigned int kb[16];
#pragma unroll
    for (int i = 0; i < 16; ++i) kb[i] = ford(v[i]);

    // --- 3-level radix descent: find 24-bit prefix of the 32nd-largest key ---
    unsigned inmask = 0xFFFFu;  // elements still in the boundary subset
    unsigned need = 32, prefix = 0, lasth = 0;
#pragma unroll
    for (int level = 0; level < 3; ++level) {
        int shift = 24 - level * 8;
        ((uint4*)h)[lane] = make_uint4(0u, 0u, 0u, 0u);
        __syncthreads();
#pragma unroll
        for (int i = 0; i < 16; ++i)
            if ((inmask >> i) & 1u) atomicAdd(&h[(kb[i] >> shift) & 0xFFu], 1u);
        __syncthreads();
        uint4 hv = ((const uint4*)h)[lane];  // bins 4*lane .. 4*lane+3
        unsigned sl = hv.x + hv.y + hv.z + hv.w;
        unsigned S = sl;  // suffix-inclusive scan: sum over lanes >= lane
#pragma unroll
        for (int off = 1; off < 64; off <<= 1) {
            unsigned o = __shfl_down(S, off);
            if (lane + off < 64) S += o;
        }
        unsigned above = S - sl;  // sum over lanes > lane
        unsigned cg3 = above + hv.w;
        unsigned cg2 = cg3 + hv.z;
        unsigned cg1 = cg2 + hv.y;
        unsigned cg0 = cg1 + hv.x;
        // local best bin = highest b in this lane with cnt_ge(b) >= need
        unsigned pack = 0;
        if      (cg3 >= need) pack = ((4u * lane + 3u) << 12) | cg3;
        else if (cg2 >= need) pack = ((4u * lane + 2u) << 12) | cg2;
        else if (cg1 >= need) pack = ((4u * lane + 1u) << 12) | cg1;
        else if (cg0 >= need) pack = ((4u * lane + 0u) << 12) | cg0;
#pragma unroll
        for (int s = 32; s; s >>= 1) {
            unsigned o = __shfl_xor(pack, s);
            pack = o > pack ? o : pack;
        }
        unsigned bstar = pack >> 12, cstar = pack & 0xFFFu;
        unsigned hstar = h[bstar];       // broadcast read
        need -= (cstar - hstar);         // strictly-above-bucket winners
        prefix = (prefix << 8) | bstar;
        lasth = hstar;
        unsigned nm = 0;
#pragma unroll
        for (int i = 0; i < 16; ++i)
            if (((inmask >> i) & 1u) && ((kb[i] >> shift) & 0xFFu) == bstar)
                nm |= 1u << i;
        inmask = nm;
        __syncthreads();  // protect h[] reads vs next level's zeroing
    }

    // --- boundary set: elements with (kb >> 8) == prefix, count == lasth -----
    unsigned winmask = 0;
    if (lasth == need) {
        winmask = inmask;  // whole boundary set wins
    } else {
        // serial top-`need` with full 64-bit (key, ~idx) ordering
        unsigned avail = inmask;
        unsigned long long best = 0ULL;
#pragma unroll
        for (int i = 0; i < 16; ++i)
            if ((avail >> i) & 1u) {
                int j = (i >> 2) * 256 + lane * 4 + (i & 3);
                unsigned long long k64 =
                    ((unsigned long long)kb[i] << 32) | (unsigned int)(~j);
                best = k64 > best ? k64 : best;
            }
        for (unsigned k = 0; k < need; ++k) {
            unsigned long long w = best;
#pragma unroll
            for (int s = 32; s; s >>= 1) {
                unsigned long long o = __shfl_xor(w, s);
                if (o > w) w = o;
            }
            if (best == w) {  // unique winner lane (keys globally unique)
                unsigned long long nb = 0ULL;
#pragma unroll
                for (int i = 0; i < 16; ++i)
                    if ((avail >> i) & 1u) {
                        int j = (i >> 2) * 256 + lane * 4 + (i & 3);
                        unsigned long long k64 =
                            ((unsigned long long)kb[i] << 32) | (unsigned int)(~j);
                        if (k64 == w) { winmask |= 1u << i; avail &= ~(1u << i); }
                        else nb = k64 > nb ? k64 : nb;
                    }
                best = nb;
            }
        }
    }

    // --- emit the 32 winners (arbitrary order; consumer is order-invariant) --
    if (lane == 0) wcnt[wave] = 0;
#pragma unroll
    for (int i = 0; i < 16; ++i) {
        bool wn = ((kb[i] >> 8) > prefix) || ((winmask >> i) & 1u);
        if (wn) {
            unsigned slot = atomicAdd(&wcnt[wave], 1u);
            int j = (i >> 2) * 256 + lane * 4 + (i & 3);
            tidx[(size_t)rb * 32 + slot] = (unsigned int)j;
            tval[(size_t)rb * 32 + slot] = __expf(v[i] - rmax) / rsum;
        }
    }
}

// ---------------- final: out = scatter(sov * x.wT[soi]) + sum_k siv_k*x_c*W[c,:] + bias
__global__ __launch_bounds__(256) void final_k(
    const float* __restrict__ x, const float* __restrict__ W,
    const float* __restrict__ wT, const float* __restrict__ bias,
    const unsigned int* __restrict__ tidx, const float* __restrict__ tval,
    float* __restrict__ out) {
    int n = blockIdx.x, t = threadIdx.x, wave = t >> 6, lane = t & 63;
    __shared__ float xr[1024];
    __shared__ float dres[32];
    __shared__ unsigned int gidx[32]; __shared__ float gval[32];
    __shared__ unsigned int iidx[32]; __shared__ float ival[32];

    ((float4*)xr)[t] = ((const float4*)(x + (size_t)n * 1024))[t];
    if (t < 32) {
        gidx[t] = tidx[(size_t)n * 32 + t];
        gval[t] = tval[(size_t)n * 32 + t];
    } else if (t < 64) {
        int k = t - 32;
        iidx[k] = tidx[((size_t)4096 + n) * 32 + k];
        ival[k] = tval[((size_t)4096 + n) * 32 + k];
    }
    __syncthreads();  // B1

    if (t < 32) ival[t] *= xr[iidx[t]];  // g_k = s_v_in * x[c_k]

    // out-branch: 32 gathered dot products, 8 per wave
    const float4* xr4 = (const float4*)xr;
#pragma unroll
    for (int d8 = 0; d8 < 8; ++d8) {
        int d = wave * 8 + d8;
        const float4* wrow = (const float4*)(wT + (size_t)gidx[d] * 1024);
        float s = 0.f;
#pragma unroll
        for (int q = 0; q < 4; ++q) {
            float4 a = wrow[q * 64 + lane];
            float4 b = xr4[q * 64 + lane];
            s += a.x * b.x + a.y * b.y + a.z * b.z + a.w * b.w;
        }
#pragma unroll
        for (int sft = 32; sft; sft >>= 1) s += __shfl_xor(s, sft);
        if (lane == 0) dres[d] = s * gval[d];
    }
    __syncthreads();  // B2: ival final, dres written, xr reads done

    // in-branch + bias (registers)
    float4 acc = ((const float4*)bias)[t];
    for (int k = 0; k < 32; ++k) {
        float g = ival[k];
        unsigned int c = iidx[k];
        float4 wr = ((const float4*)(W + (size_t)c * 1024))[t];
        acc.x = fmaf(g, wr.x, acc.x); acc.y = fmaf(g, wr.y, acc.y);
        acc.z = fmaf(g, wr.z, acc.z); acc.w = fmaf(g, wr.w, acc.w);
    }
    ((float4*)xr)[t] = acc;  // reuse xr as output row
    __syncthreads();  // B3
    if (t < 32) xr[gidx[t]] += dres[t];  // unique indices, no race
    __syncthreads();  // B4
    ((float4*)(out + (size_t)n * 1024))[t] = ((float4*)xr)[t];
}

extern "C" void kernel_launch(void* const* d_in, const int* in_sizes, int n_in,
                              void* d_out, int out_size, void* d_ws, size_t ws_size,
                              hipStream_t stream) {
    const float* x        = (const float*)d_in[0];
    const float* W        = (const float*)d_in[1];
    const float* bias     = (const float*)d_in[2];
    const float* so_cw    = (const float*)d_in[3];
    const float* so_cb    = (const float*)d_in[4];
    const float* so_gm    = (const float*)d_in[5];
    const float* so_bt    = (const float*)d_in[6];
    const float* so_lw    = (const float*)d_in[7];
    const float* so_lb    = (const float*)d_in[8];
    const float* si_cw    = (const float*)d_in[9];
    const float* si_cb    = (const float*)d_in[10];
    const float* si_gm    = (const float*)d_in[11];
    const float* si_bt    = (const float*)d_in[12];
    const float* si_lw    = (const float*)d_in[13];
    const float* si_lb    = (const float*)d_in[14];
    float* out = (float*)d_out;

    float* ws       = (float*)d_ws;
    float* wT       = ws;                       // 1048576
    float* linT     = ws + 1048576;             // 2 x 262144
    float* xc       = ws + 1572864;             // 2 x 1048576
    float* partials = ws + 3670016;             // 262144
    float* sc       = ws + 3932160;             // 1024
    float* logits   = ws + 3933184;             // 8388608
    unsigned int* tidx = (unsigned int*)(ws + 12321792);  // 262144
    float* tval     = ws + 12583936;            // 262144

    transpose_k<<<dim3(32, 32), dim3(32, 8), 0, stream>>>(W, wT, 1024, 1024);
    transpose_k<<<dim3(8, 32), dim3(32, 8), 0, stream>>>(so_lw, linT, 1024, 256);
    transpose_k<<<dim3(8, 32), dim3(32, 8), 0, stream>>>(si_lw, linT + 262144, 1024, 256);
    conv_stats_k<<<256, 256, 0, stream>>>(x, so_cw, so_cb, si_cw, si_cb, xc, partials);
    stats_k<<<2, 256, 0, stream>>>(partials, so_gm, so_bt, si_gm, si_bt, sc);
    logits_k<<<dim3(256, 2), 256, 0, stream>>>(xc, sc, linT, so_lb, si_lb, logits);
    topk_k<<<2048, 256, 0, stream>>>(logits, tidx, tval);
    final_k<<<4096, 256, 0, stream>>>(x, W, wT, bias, tidx, tval, out);
}

// Round 5
// 187.752 us; speedup vs baseline: 1.0869x; 1.0869x over previous
//
#include <hip/hip_runtime.h>
#include <math.h>

// Problem: B=4, L=1024, C1=1024, C2=1024, K=32, K_IN=32, g=256.
// N = B*L = 4096 rows. All f32.
//
// ws layout (floats):
//   wT      [1024*1024]            off 0
//   linT    [2][256*1024]          off 1048576
//   xc      [2][4096*256]          off 1572864
//   partials[256][4][256]          off 3670016
//   sc      [2][2][256]            off 3932160
//   logits  [8192][1024]           off 3933184
//   tidx    [8192][32] (u32)       off 12321792
//   tval    [8192][32]             off 12583936
// total ~12.85M floats = 51.4 MB

__device__ __forceinline__ unsigned int ford(float f) {
    unsigned int b = __float_as_uint(f);
    return (b & 0x80000000u) ? ~b : (b | 0x80000000u);
}

// ---------------- generic 32x32 tiled transpose: in (R,C) -> out (C,R) -------
__global__ __launch_bounds__(256) void transpose_k(const float* __restrict__ in,
                                                   float* __restrict__ out,
                                                   int R, int C) {
    __shared__ float tile[32][33];
    int c0 = blockIdx.x * 32, r0 = blockIdx.y * 32;
    int tx = threadIdx.x, ty = threadIdx.y;  // block (32,8)
#pragma unroll
    for (int i = 0; i < 32; i += 8)
        tile[ty + i][tx] = in[(size_t)(r0 + ty + i) * C + c0 + tx];
    __syncthreads();
#pragma unroll
    for (int i = 0; i < 32; i += 8)
        out[(size_t)(c0 + ty + i) * R + r0 + tx] = tile[tx][ty + i];
}

// ---------------- grouped 1x1 conv (4->1) for both branches + partial stats --
__global__ __launch_bounds__(256) void conv_stats_k(
    const float* __restrict__ x,
    const float* __restrict__ so_w, const float* __restrict__ so_b,
    const float* __restrict__ si_w, const float* __restrict__ si_b,
    float* __restrict__ xc, float* __restrict__ partials) {
    int g = threadIdx.x;          // channel 0..255
    int n0 = blockIdx.x * 16;     // 256 blocks x 16 rows
    float4 wo = ((const float4*)so_w)[g]; float bo = so_b[g];
    float4 wi = ((const float4*)si_w)[g]; float bi = si_b[g];
    float so_s = 0.f, so_q = 0.f, si_s = 0.f, si_q = 0.f;
#pragma unroll
    for (int r = 0; r < 16; ++r) {
        int n = n0 + r;
        float4 xv = ((const float4*)x)[n * 256 + g];
        float co = fmaf(xv.x, wo.x, fmaf(xv.y, wo.y, fmaf(xv.z, wo.z, fmaf(xv.w, wo.w, bo))));
        float ci = fmaf(xv.x, wi.x, fmaf(xv.y, wi.y, fmaf(xv.z, wi.z, fmaf(xv.w, wi.w, bi))));
        xc[n * 256 + g] = co;
        xc[1048576 + n * 256 + g] = ci;
        so_s += co; so_q += co * co;
        si_s += ci; si_q += ci * ci;
    }
    int b = blockIdx.x;
    partials[(b * 4 + 0) * 256 + g] = so_s;
    partials[(b * 4 + 1) * 256 + g] = so_q;
    partials[(b * 4 + 2) * 256 + g] = si_s;
    partials[(b * 4 + 3) * 256 + g] = si_q;
}

// ---------------- finalize BN stats -> per-channel scale/shift ---------------
__global__ __launch_bounds__(256) void stats_k(
    const float* __restrict__ partials,
    const float* __restrict__ g_so, const float* __restrict__ b_so,
    const float* __restrict__ g_si, const float* __restrict__ b_si,
    float* __restrict__ sc) {
    int g = threadIdx.x;
    int br = blockIdx.x;  // 0 = so, 1 = si
    float s = 0.f, q = 0.f;
    for (int b = 0; b < 256; ++b) {
        s += partials[(b * 4 + br * 2 + 0) * 256 + g];
        q += partials[(b * 4 + br * 2 + 1) * 256 + g];
    }
    float mean = s * (1.f / 4096.f);
    float var  = q * (1.f / 4096.f) - mean * mean;  // biased, matches ref
    float rstd = rsqrtf(var + 1e-5f);
    float gm = br ? g_si[g] : g_so[g];
    float bt = br ? b_si[g] : b_so[g];
    float scale = gm * rstd;
    sc[br * 512 + g]       = scale;
    sc[br * 512 + 256 + g] = fmaf(-mean, scale, bt);
}

// ---------------- BN+GELU fused + (4096x256)@(256x1024) f32 GEMM -------------
// 8x8 per-thread tile (DS-optimal: 2 ds_read_b128 per k feed 64 FMAs), all of
// xa staged in LDS ONCE (16 rows x 256 k = 16 KB, single barrier), and the
// 256-step k-loop software-pipelined one step ahead (ping-pong registers) so
// each L2 weight load is covered by a 64-FMA block. 2 waves/SIMD is structural
// (2048 waves total) -> latency hiding must come from this ILP.
//   DS 20us | VALU 27us (limiter) | L2 weights 512MB ~15us, all overlapped.
__global__ __launch_bounds__(256, 2) void logits_k(
    const float* __restrict__ xc, const float* __restrict__ sc,
    const float* __restrict__ linT,
    const float* __restrict__ so_lb, const float* __restrict__ si_lb,
    float* __restrict__ logits) {
    int t = threadIdx.x;
    int n0 = blockIdx.x * 16;
    int br = blockIdx.y;
    int wave = t >> 6, lane = t & 63;
    int rh = wave >> 1;                 // rows 8*rh .. 8*rh+7
    int ch = wave & 1;                  // col half
    int col0 = ch * 512 + lane * 4;     // cols col0..+3 and col0+256..+259

    __shared__ float xaT[256][16];      // [k][row] = 16 KB

    const float* xcb = xc + (size_t)br * 1048576;
    const float* lt  = linT + (size_t)br * 262144;

    // ---- stage ALL of xa^T (BN + exact GELU fused): 2 rows x 8 k per thread
    {
        int kb8 = (t >> 3) * 8;         // k base 0..248
        int r2  = (t & 7) * 2;          // rows r2, r2+1
        float4 sc0 = *(const float4*)&sc[br * 512 + kb8];
        float4 sc1 = *(const float4*)&sc[br * 512 + kb8 + 4];
        float4 sh0 = *(const float4*)&sc[br * 512 + 256 + kb8];
        float4 sh1 = *(const float4*)&sc[br * 512 + 256 + kb8 + 4];
        float4 ca0 = *(const float4*)&xcb[(n0 + r2) * 256 + kb8];
        float4 ca1 = *(const float4*)&xcb[(n0 + r2) * 256 + kb8 + 4];
        float4 cb0 = *(const float4*)&xcb[(n0 + r2 + 1) * 256 + kb8];
        float4 cb1 = *(const float4*)&xcb[(n0 + r2 + 1) * 256 + kb8 + 4];
#pragma unroll
        for (int j = 0; j < 8; ++j) {
            float scl = j < 4 ? (&sc0.x)[j] : (&sc1.x)[j - 4];
            float shf = j < 4 ? (&sh0.x)[j] : (&sh1.x)[j - 4];
            float c0  = j < 4 ? (&ca0.x)[j] : (&ca1.x)[j - 4];
            float c1  = j < 4 ? (&cb0.x)[j] : (&cb1.x)[j - 4];
            float z0 = fmaf(c0, scl, shf);
            float z1 = fmaf(c1, scl, shf);
            float2 gw;
            gw.x = 0.5f * z0 * (1.f + erff(z0 * 0.70710678f));
            gw.y = 0.5f * z1 * (1.f + erff(z1 * 0.70710678f));
            *(float2*)&xaT[kb8 + j][r2] = gw;
        }
    }
    __syncthreads();  // the only barrier

    float4 accA[2][4];                  // [row-quad][col i], components = rows
    float4 accB[2][4];
#pragma unroll
    for (int a = 0; a < 2; ++a)
#pragma unroll
        for (int i = 0; i < 4; ++i) {
            accA[a][i] = make_float4(0.f, 0.f, 0.f, 0.f);
            accB[a][i] = make_float4(0.f, 0.f, 0.f, 0.f);
        }

#define FMA_BLOCK(A0, A1, WA, WB)                                   \
    {                                                               \
        _Pragma("unroll")                                           \
        for (int i = 0; i < 4; ++i) {                               \
            float wa = (&WA.x)[i], wb = (&WB.x)[i];                 \
            accA[0][i].x = fmaf(A0.x, wa, accA[0][i].x);            \
            accA[0][i].y = fmaf(A0.y, wa, accA[0][i].y);            \
            accA[0][i].z = fmaf(A0.z, wa, accA[0][i].z);            \
            accA[0][i].w = fmaf(A0.w, wa, accA[0][i].w);            \
            accA[1][i].x = fmaf(A1.x, wa, accA[1][i].x);            \
            accA[1][i].y = fmaf(A1.y, wa, accA[1][i].y);            \
            accA[1][i].z = fmaf(A1.z, wa, accA[1][i].z);            \
            accA[1][i].w = fmaf(A1.w, wa, accA[1][i].w);            \
            accB[0][i].x = fmaf(A0.x, wb, accB[0][i].x);            \
            accB[0][i].y = fmaf(A0.y, wb, accB[0][i].y);            \
            accB[0][i].z = fmaf(A0.z, wb, accB[0][i].z);            \
            accB[0][i].w = fmaf(A0.w, wb, accB[0][i].w);            \
            accB[1][i].x = fmaf(A1.x, wb, accB[1][i].x);            \
            accB[1][i].y = fmaf(A1.y, wb, accB[1][i].y);            \
            accB[1][i].z = fmaf(A1.z, wb, accB[1][i].z);            \
            accB[1][i].w = fmaf(A1.w, wb, accB[1][i].w);            \
        }                                                           \
    }

    // ---- software-pipelined k-loop: prefetch k+1 while FMA-ing k ----
    float4 wA0 = *(const float4*)&lt[col0];
    float4 wB0 = *(const float4*)&lt[col0 + 256];
    float4 a00 = *(const float4*)&xaT[0][8 * rh];
    float4 a10 = *(const float4*)&xaT[0][8 * rh + 4];
    for (int k = 0; k < 256; k += 2) {
        int kp1 = k + 1;
        float4 wA1 = *(const float4*)&lt[(size_t)kp1 * 1024 + col0];
        float4 wB1 = *(const float4*)&lt[(size_t)kp1 * 1024 + col0 + 256];
        float4 a01 = *(const float4*)&xaT[kp1][8 * rh];
        float4 a11 = *(const float4*)&xaT[kp1][8 * rh + 4];
        FMA_BLOCK(a00, a10, wA0, wB0);
        int kp2 = (k + 2) & 255;  // wraps at the end; prefetched regs unused
        wA0 = *(const float4*)&lt[(size_t)kp2 * 1024 + col0];
        wB0 = *(const float4*)&lt[(size_t)kp2 * 1024 + col0 + 256];
        a00 = *(const float4*)&xaT[kp2][8 * rh];
        a10 = *(const float4*)&xaT[kp2][8 * rh + 4];
        FMA_BLOCK(a01, a11, wA1, wB1);
    }
#undef FMA_BLOCK

    const float* lb = br ? si_lb : so_lb;
    float4 lbA = *(const float4*)&lb[col0];
    float4 lbB = *(const float4*)&lb[col0 + 256];
    float* lg = logits + ((size_t)br * 4096 + n0) * 1024;
#pragma unroll
    for (int a = 0; a < 2; ++a)
#pragma unroll
        for (int ri = 0; ri < 4; ++ri) {
            int row = 8 * rh + 4 * a + ri;
            float4 vA, vB;
            vA.x = (&accA[a][0].x)[ri] + lbA.x;
            vA.y = (&accA[a][1].x)[ri] + lbA.y;
            vA.z = (&accA[a][2].x)[ri] + lbA.z;
            vA.w = (&accA[a][3].x)[ri] + lbA.w;
            vB.x = (&accB[a][0].x)[ri] + lbB.x;
            vB.y = (&accB[a][1].x)[ri] + lbB.y;
            vB.z = (&accB[a][2].x)[ri] + lbB.z;
            vB.w = (&accB[a][3].x)[ri] + lbB.w;
            *(float4*)&lg[(size_t)row * 1024 + col0]       = vA;
            *(float4*)&lg[(size_t)row * 1024 + col0 + 256] = vB;
        }
}

// ---------------- softmax stats + exact top-32 per row-branch ----------------
// One wave per row-branch. 3-level radix-histogram select on the orderable key
// (8 bits/level, 24 bits total), then a tiny serial argmax over the boundary
// set with full 64-bit (key, ~idx) ordering -> selected SET exactly matches
// jax.lax.top_k (ties -> lowest index). Output order is arbitrary (consumer is
// order-invariant).
__global__ __launch_bounds__(256) void topk_k(const float* __restrict__ logits,
                                              unsigned int* __restrict__ tidx,
                                              float* __restrict__ tval) {
    __shared__ unsigned int hist[4][256];
    __shared__ unsigned int wcnt[4];
    int wave = threadIdx.x >> 6, lane = threadIdx.x & 63;
    int rb = blockIdx.x * 4 + wave;  // 0..8191
    unsigned int* h = hist[wave];

    const float4* lg = (const float4*)(logits + (size_t)rb * 1024);
    float v[16];
#pragma unroll
    for (int q = 0; q < 4; ++q) {
        float4 f = lg[q * 64 + lane];
        v[q * 4 + 0] = f.x; v[q * 4 + 1] = f.y;
        v[q * 4 + 2] = f.z; v[q * 4 + 3] = f.w;
    }
    // row max
    float rmax = v[0];
#pragma unroll
    for (int i = 1; i < 16; ++i) rmax = fmaxf(rmax, v[i]);
#pragma unroll
    for (int s = 32; s; s >>= 1) rmax = fmaxf(rmax, __shfl_xor(rmax, s));
    // softmax denominator
    float rsum = 0.f;
#pragma unroll
    for (int i = 0; i < 16; ++i) rsum += __expf(v[i] - rmax);
#pragma unroll
    for (int s = 32; s; s >>= 1) rsum += __shfl_xor(rsum, s);

    unsigned int kb[16];
#pragma unroll
    for (int i = 0; i < 16; ++i) kb[i] = ford(v[i]);

    // --- 3-level radix descent: find 24-bit prefix of the 32nd-largest key ---
    unsigned inmask = 0xFFFFu;  // elements still in the boundary subset
    unsigned need = 32, prefix = 0, lasth = 0;
#pragma unroll
    for (int level = 0; level < 3; ++level) {
        int shift = 24 - level * 8;
        ((uint4*)h)[lane] = make_uint4(0u, 0u, 0u, 0u);
        __syncthreads();
#pragma unroll
        for (int i = 0; i < 16; ++i)
            if ((inmask >> i) & 1u) atomicAdd(&h[(kb[i] >> shift) & 0xFFu], 1u);
        __syncthreads();
        uint4 hv = ((const uint4*)h)[lane];  // bins 4*lane .. 4*lane+3
        unsigned sl = hv.x + hv.y + hv.z + hv.w;
        unsigned S = sl;  // suffix-inclusive scan: sum over lanes >= lane
#pragma unroll
        for (int off = 1; off < 64; off <<= 1) {
            unsigned o = __shfl_down(S, off);
            if (lane + off < 64) S += o;
        }
        unsigned above = S - sl;  // sum over lanes > lane
        unsigned cg3 = above + hv.w;
        unsigned cg2 = cg3 + hv.z;
        unsigned cg1 = cg2 + hv.y;
        unsigned cg0 = cg1 + hv.x;
        // local best bin = highest b in this lane with cnt_ge(b) >= need
        unsigned pack = 0;
        if      (cg3 >= need) pack = ((4u * lane + 3u) << 12) | cg3;
        else if (cg2 >= need) pack = ((4u * lane + 2u) << 12) | cg2;
        else if (cg1 >= need) pack = ((4u * lane + 1u) << 12) | cg1;
        else if (cg0 >= need) pack = ((4u * lane + 0u) << 12) | cg0;
#pragma unroll
        for (int s = 32; s; s >>= 1) {
            unsigned o = __shfl_xor(pack, s);
            pack = o > pack ? o : pack;
        }
        unsigned bstar = pack >> 12, cstar = pack & 0xFFFu;
        unsigned hstar = h[bstar];       // broadcast read
        need -= (cstar - hstar);         // strictly-above-bucket winners
        prefix = (prefix << 8) | bstar;
        lasth = hstar;
        unsigned nm = 0;
#pragma unroll
        for (int i = 0; i < 16; ++i)
            if (((inmask >> i) & 1u) && ((kb[i] >> shift) & 0xFFu) == bstar)
                nm |= 1u << i;
        inmask = nm;
        __syncthreads();  // protect h[] reads vs next level's zeroing
    }

    // --- boundary set: elements with (kb >> 8) == prefix, count == lasth -----
    unsigned winmask = 0;
    if (lasth == need) {
        winmask = inmask;  // whole boundary set wins
    } else {
        // serial top-`need` with full 64-bit (key, ~idx) ordering
        unsigned avail = inmask;
        unsigned long long best = 0ULL;
#pragma unroll
        for (int i = 0; i < 16; ++i)
            if ((avail >> i) & 1u) {
                int j = (i >> 2) * 256 + lane * 4 + (i & 3);
                unsigned long long k64 =
                    ((unsigned long long)kb[i] << 32) | (unsigned int)(~j);
                best = k64 > best ? k64 : best;
            }
        for (unsigned k = 0; k < need; ++k) {
            unsigned long long w = best;
#pragma unroll
            for (int s = 32; s; s >>= 1) {
                unsigned long long o = __shfl_xor(w, s);
                if (o > w) w = o;
            }
            if (best == w) {  // unique winner lane (keys globally unique)
                unsigned long long nb = 0ULL;
#pragma unroll
                for (int i = 0; i < 16; ++i)
                    if ((avail >> i) & 1u) {
                        int j = (i >> 2) * 256 + lane * 4 + (i & 3);
                        unsigned long long k64 =
                            ((unsigned long long)kb[i] << 32) | (unsigned int)(~j);
                        if (k64 == w) { winmask |= 1u << i; avail &= ~(1u << i); }
                        else nb = k64 > nb ? k64 : nb;
                    }
                best = nb;
            }
        }
    }

    // --- emit the 32 winners (arbitrary order; consumer is order-invariant) --
    if (lane == 0) wcnt[wave] = 0;
#pragma unroll
    for (int i = 0; i < 16; ++i) {
        bool wn = ((kb[i] >> 8) > prefix) || ((winmask >> i) & 1u);
        if (wn) {
            unsigned slot = atomicAdd(&wcnt[wave], 1u);
            int j = (i >> 2) * 256 + lane * 4 + (i & 3);
            tidx[(size_t)rb * 32 + slot] = (unsigned int)j;
            tval[(size_t)rb * 32 + slot] = __expf(v[i] - rmax) / rsum;
        }
    }
}

// ---------------- final: out = scatter(sov * x.wT[soi]) + sum_k siv_k*x_c*W[c,:] + bias
__global__ __launch_bounds__(256) void final_k(
    const float* __restrict__ x, const float* __restrict__ W,
    const float* __restrict__ wT, const float* __restrict__ bias,
    const unsigned int* __restrict__ tidx, const float* __restrict__ tval,
    float* __restrict__ out) {
    int n = blockIdx.x, t = threadIdx.x, wave = t >> 6, lane = t & 63;
    __shared__ float xr[1024];
    __shared__ float dres[32];
    __shared__ unsigned int gidx[32]; __shared__ float gval[32];
    __shared__ unsigned int iidx[32]; __shared__ float ival[32];

    ((float4*)xr)[t] = ((const float4*)(x + (size_t)n * 1024))[t];
    if (t < 32) {
        gidx[t] = tidx[(size_t)n * 32 + t];
        gval[t] = tval[(size_t)n * 32 + t];
    } else if (t < 64) {
        int k = t - 32;
        iidx[k] = tidx[((size_t)4096 + n) * 32 + k];
        ival[k] = tval[((size_t)4096 + n) * 32 + k];
    }
    __syncthreads();  // B1

    if (t < 32) ival[t] *= xr[iidx[t]];  // g_k = s_v_in * x[c_k]

    // out-branch: 32 gathered dot products, 8 per wave
    const float4* xr4 = (const float4*)xr;
#pragma unroll
    for (int d8 = 0; d8 < 8; ++d8) {
        int d = wave * 8 + d8;
        const float4* wrow = (const float4*)(wT + (size_t)gidx[d] * 1024);
        float s = 0.f;
#pragma unroll
        for (int q = 0; q < 4; ++q) {
            float4 a = wrow[q * 64 + lane];
            float4 b = xr4[q * 64 + lane];
            s += a.x * b.x + a.y * b.y + a.z * b.z + a.w * b.w;
        }
#pragma unroll
        for (int sft = 32; sft; sft >>= 1) s += __shfl_xor(s, sft);
        if (lane == 0) dres[d] = s * gval[d];
    }
    __syncthreads();  // B2: ival final, dres written, xr reads done

    // in-branch + bias (registers)
    float4 acc = ((const float4*)bias)[t];
    for (int k = 0; k < 32; ++k) {
        float g = ival[k];
        unsigned int c = iidx[k];
        float4 wr = ((const float4*)(W + (size_t)c * 1024))[t];
        acc.x = fmaf(g, wr.x, acc.x); acc.y = fmaf(g, wr.y, acc.y);
        acc.z = fmaf(g, wr.z, acc.z); acc.w = fmaf(g, wr.w, acc.w);
    }
    ((float4*)xr)[t] = acc;  // reuse xr as output row
    __syncthreads();  // B3
    if (t < 32) xr[gidx[t]] += dres[t];  // unique indices, no race
    __syncthreads();  // B4
    ((float4*)(out + (size_t)n * 1024))[t] = ((float4*)xr)[t];
}

extern "C" void kernel_launch(void* const* d_in, const int* in_sizes, int n_in,
                              void* d_out, int out_size, void* d_ws, size_t ws_size,
                              hipStream_t stream) {
    const float* x        = (const float*)d_in[0];
    const float* W        = (const float*)d_in[1];
    const float* bias     = (const float*)d_in[2];
    const float* so_cw    = (const float*)d_in[3];
    const float* so_cb    = (const float*)d_in[4];
    const float* so_gm    = (const float*)d_in[5];
    const float* so_bt    = (const float*)d_in[6];
    const float* so_lw    = (const float*)d_in[7];
    const float* so_lb    = (const float*)d_in[8];
    const float* si_cw    = (const float*)d_in[9];
    const float* si_cb    = (const float*)d_in[10];
    const float* si_gm    = (const float*)d_in[11];
    const float* si_bt    = (const float*)d_in[12];
    const float* si_lw    = (const float*)d_in[13];
    const float* si_lb    = (const float*)d_in[14];
    float* out = (float*)d_out;

    float* ws       = (float*)d_ws;
    float* wT       = ws;                       // 1048576
    float* linT     = ws + 1048576;             // 2 x 262144
    float* xc       = ws + 1572864;             // 2 x 1048576
    float* partials = ws + 3670016;             // 262144
    float* sc       = ws + 3932160;             // 1024
    float* logits   = ws + 3933184;             // 8388608
    unsigned int* tidx = (unsigned int*)(ws + 12321792);  // 262144
    float* tval     = ws + 12583936;            // 262144

    transpose_k<<<dim3(32, 32), dim3(32, 8), 0, stream>>>(W, wT, 1024, 1024);
    transpose_k<<<dim3(8, 32), dim3(32, 8), 0, stream>>>(so_lw, linT, 1024, 256);
    transpose_k<<<dim3(8, 32), dim3(32, 8), 0, stream>>>(si_lw, linT + 262144, 1024, 256);
    conv_stats_k<<<256, 256, 0, stream>>>(x, so_cw, so_cb, si_cw, si_cb, xc, partials);
    stats_k<<<2, 256, 0, stream>>>(partials, so_gm, so_bt, si_gm, si_bt, sc);
    logits_k<<<dim3(256, 2), 256, 0, stream>>>(xc, sc, linT, so_lb, si_lb, logits);
    topk_k<<<2048, 256, 0, stream>>>(logits, tidx, tval);
    final_k<<<4096, 256, 0, stream>>>(x, W, wT, bias, tidx, tval, out);
}

// Round 6
// 170.458 us; speedup vs baseline: 1.1972x; 1.1015x over previous
//
#include <hip/hip_runtime.h>
#include <math.h>

// Problem: B=4, L=1024, C1=1024, C2=1024, K=32, K_IN=32, g=256.
// N = B*L = 4096 rows. All f32.
//
// ws layout (floats):
//   wT      [1024*1024]            off 0
//   linT    [2][256*1024]          off 1048576
//   xc      [2][4096*256]          off 1572864
//   partials[256][4][256]          off 3670016
//   sc      [2][2][256]            off 3932160
//   logits  [8192][1024]           off 3933184
//   tidx    [8192][32] (u32)       off 12321792
//   tval    [8192][32]             off 12583936
// total ~12.85M floats = 51.4 MB

__device__ __forceinline__ unsigned int ford(float f) {
    unsigned int b = __float_as_uint(f);
    return (b & 0x80000000u) ? ~b : (b | 0x80000000u);
}

// ---------------- generic 32x32 tiled transpose: in (R,C) -> out (C,R) -------
__global__ __launch_bounds__(256) void transpose_k(const float* __restrict__ in,
                                                   float* __restrict__ out,
                                                   int R, int C) {
    __shared__ float tile[32][33];
    int c0 = blockIdx.x * 32, r0 = blockIdx.y * 32;
    int tx = threadIdx.x, ty = threadIdx.y;  // block (32,8)
#pragma unroll
    for (int i = 0; i < 32; i += 8)
        tile[ty + i][tx] = in[(size_t)(r0 + ty + i) * C + c0 + tx];
    __syncthreads();
#pragma unroll
    for (int i = 0; i < 32; i += 8)
        out[(size_t)(c0 + ty + i) * R + r0 + tx] = tile[tx][ty + i];
}

// ---------------- grouped 1x1 conv (4->1) for both branches + partial stats --
__global__ __launch_bounds__(256) void conv_stats_k(
    const float* __restrict__ x,
    const float* __restrict__ so_w, const float* __restrict__ so_b,
    const float* __restrict__ si_w, const float* __restrict__ si_b,
    float* __restrict__ xc, float* __restrict__ partials) {
    int g = threadIdx.x;          // channel 0..255
    int n0 = blockIdx.x * 16;     // 256 blocks x 16 rows
    float4 wo = ((const float4*)so_w)[g]; float bo = so_b[g];
    float4 wi = ((const float4*)si_w)[g]; float bi = si_b[g];
    float so_s = 0.f, so_q = 0.f, si_s = 0.f, si_q = 0.f;
#pragma unroll
    for (int r = 0; r < 16; ++r) {
        int n = n0 + r;
        float4 xv = ((const float4*)x)[n * 256 + g];
        float co = fmaf(xv.x, wo.x, fmaf(xv.y, wo.y, fmaf(xv.z, wo.z, fmaf(xv.w, wo.w, bo))));
        float ci = fmaf(xv.x, wi.x, fmaf(xv.y, wi.y, fmaf(xv.z, wi.z, fmaf(xv.w, wi.w, bi))));
        xc[n * 256 + g] = co;
        xc[1048576 + n * 256 + g] = ci;
        so_s += co; so_q += co * co;
        si_s += ci; si_q += ci * ci;
    }
    int b = blockIdx.x;
    partials[(b * 4 + 0) * 256 + g] = so_s;
    partials[(b * 4 + 1) * 256 + g] = so_q;
    partials[(b * 4 + 2) * 256 + g] = si_s;
    partials[(b * 4 + 3) * 256 + g] = si_q;
}

// ---------------- finalize BN stats -> per-channel scale/shift ---------------
__global__ __launch_bounds__(256) void stats_k(
    const float* __restrict__ partials,
    const float* __restrict__ g_so, const float* __restrict__ b_so,
    const float* __restrict__ g_si, const float* __restrict__ b_si,
    float* __restrict__ sc) {
    int g = threadIdx.x;
    int br = blockIdx.x;  // 0 = so, 1 = si
    float s = 0.f, q = 0.f;
    for (int b = 0; b < 256; ++b) {
        s += partials[(b * 4 + br * 2 + 0) * 256 + g];
        q += partials[(b * 4 + br * 2 + 1) * 256 + g];
    }
    float mean = s * (1.f / 4096.f);
    float var  = q * (1.f / 4096.f) - mean * mean;  // biased, matches ref
    float rstd = rsqrtf(var + 1e-5f);
    float gm = br ? g_si[g] : g_so[g];
    float bt = br ? b_si[g] : b_so[g];
    float scale = gm * rstd;
    sc[br * 512 + g]       = scale;
    sc[br * 512 + 256 + g] = fmaf(-mean, scale, bt);
}

// ---------------- BN+GELU fused + (4096x256)@(256x1024) f32 GEMM -------------
// 8x8 per-thread tile + SPLIT-K: block = 16 rows x 512 cols, 4 waves =
// (row-half x k-half); each wave accumulates 128 k in registers, odd-kh waves
// dump partials to LDS, even-kh waves add + write. Grid 256x2x2 = 1024 blocks
// = 4 blocks/CU = 4 waves/SIMD, so VALU (~27us), L1 (~27us) and DS (~20us)
// demand can overlap across waves instead of serializing within one wave.
__global__ __launch_bounds__(256, 4) void logits_k(
    const float* __restrict__ xc, const float* __restrict__ sc,
    const float* __restrict__ linT,
    const float* __restrict__ so_lb, const float* __restrict__ si_lb,
    float* __restrict__ logits) {
    int t = threadIdx.x;
    int n0 = blockIdx.x * 16;
    int cb = blockIdx.y;                // col half (512 cols)
    int br = blockIdx.z;
    int wave = t >> 6, lane = t & 63;
    int kh = wave & 1;                  // k half: 128 k each
    int rh = wave >> 1;                 // rows 8*rh .. 8*rh+7
    int col0 = cb * 512 + lane * 4;     // cols col0..+3 and col0+256..+259

    __shared__ float lds[8192];         // 32 KB: xaT (16KB) then reduction buf
    float (*xaT)[16] = (float(*)[16])lds;  // [256][16]

    const float* xcb = xc + (size_t)br * 1048576;
    const float* lt  = linT + (size_t)br * 262144;

    // ---- stage ALL of xa^T (BN + exact GELU fused): 2 rows x 8 k per thread
    {
        int kb8 = (t >> 3) * 8;         // k base 0..248
        int r2  = (t & 7) * 2;          // rows r2, r2+1
        float4 sc0 = *(const float4*)&sc[br * 512 + kb8];
        float4 sc1 = *(const float4*)&sc[br * 512 + kb8 + 4];
        float4 sh0 = *(const float4*)&sc[br * 512 + 256 + kb8];
        float4 sh1 = *(const float4*)&sc[br * 512 + 256 + kb8 + 4];
        float4 ca0 = *(const float4*)&xcb[(n0 + r2) * 256 + kb8];
        float4 ca1 = *(const float4*)&xcb[(n0 + r2) * 256 + kb8 + 4];
        float4 cb0 = *(const float4*)&xcb[(n0 + r2 + 1) * 256 + kb8];
        float4 cb1 = *(const float4*)&xcb[(n0 + r2 + 1) * 256 + kb8 + 4];
#pragma unroll
        for (int j = 0; j < 8; ++j) {
            float scl = j < 4 ? (&sc0.x)[j] : (&sc1.x)[j - 4];
            float shf = j < 4 ? (&sh0.x)[j] : (&sh1.x)[j - 4];
            float c0  = j < 4 ? (&ca0.x)[j] : (&ca1.x)[j - 4];
            float c1  = j < 4 ? (&cb0.x)[j] : (&cb1.x)[j - 4];
            float z0 = fmaf(c0, scl, shf);
            float z1 = fmaf(c1, scl, shf);
            float2 gw;
            gw.x = 0.5f * z0 * (1.f + erff(z0 * 0.70710678f));
            gw.y = 0.5f * z1 * (1.f + erff(z1 * 0.70710678f));
            *(float2*)&xaT[kb8 + j][r2] = gw;
        }
    }
    __syncthreads();

    float4 accA[2][4];                  // [row-quad][col i], components = rows
    float4 accB[2][4];
#pragma unroll
    for (int a = 0; a < 2; ++a)
#pragma unroll
        for (int i = 0; i < 4; ++i) {
            accA[a][i] = make_float4(0.f, 0.f, 0.f, 0.f);
            accB[a][i] = make_float4(0.f, 0.f, 0.f, 0.f);
        }

#define FMA_BLOCK(A0, A1, WA, WB)                                   \
    {                                                               \
        _Pragma("unroll")                                           \
        for (int i = 0; i < 4; ++i) {                               \
            float wa = (&WA.x)[i], wb = (&WB.x)[i];                 \
            accA[0][i].x = fmaf(A0.x, wa, accA[0][i].x);            \
            accA[0][i].y = fmaf(A0.y, wa, accA[0][i].y);            \
            accA[0][i].z = fmaf(A0.z, wa, accA[0][i].z);            \
            accA[0][i].w = fmaf(A0.w, wa, accA[0][i].w);            \
            accA[1][i].x = fmaf(A1.x, wa, accA[1][i].x);            \
            accA[1][i].y = fmaf(A1.y, wa, accA[1][i].y);            \
            accA[1][i].z = fmaf(A1.z, wa, accA[1][i].z);            \
            accA[1][i].w = fmaf(A1.w, wa, accA[1][i].w);            \
            accB[0][i].x = fmaf(A0.x, wb, accB[0][i].x);            \
            accB[0][i].y = fmaf(A0.y, wb, accB[0][i].y);            \
            accB[0][i].z = fmaf(A0.z, wb, accB[0][i].z);            \
            accB[0][i].w = fmaf(A0.w, wb, accB[0][i].w);            \
            accB[1][i].x = fmaf(A1.x, wb, accB[1][i].x);            \
            accB[1][i].y = fmaf(A1.y, wb, accB[1][i].y);            \
            accB[1][i].z = fmaf(A1.z, wb, accB[1][i].z);            \
            accB[1][i].w = fmaf(A1.w, wb, accB[1][i].w);            \
        }                                                           \
    }

    // ---- software-pipelined 128-k loop (this wave's k half) ----
    int kbeg = kh * 128;
    float4 wA0 = *(const float4*)&lt[(size_t)kbeg * 1024 + col0];
    float4 wB0 = *(const float4*)&lt[(size_t)kbeg * 1024 + col0 + 256];
    float4 a00 = *(const float4*)&xaT[kbeg][8 * rh];
    float4 a10 = *(const float4*)&xaT[kbeg][8 * rh + 4];
    for (int k = kbeg; k < kbeg + 128; k += 2) {
        int kp1 = k + 1;
        float4 wA1 = *(const float4*)&lt[(size_t)kp1 * 1024 + col0];
        float4 wB1 = *(const float4*)&lt[(size_t)kp1 * 1024 + col0 + 256];
        float4 a01 = *(const float4*)&xaT[kp1][8 * rh];
        float4 a11 = *(const float4*)&xaT[kp1][8 * rh + 4];
        FMA_BLOCK(a00, a10, wA0, wB0);
        int kp2 = ((k + 2 - kbeg) & 127) + kbeg;  // wraps; last prefetch unused
        wA0 = *(const float4*)&lt[(size_t)kp2 * 1024 + col0];
        wB0 = *(const float4*)&lt[(size_t)kp2 * 1024 + col0 + 256];
        a00 = *(const float4*)&xaT[kp2][8 * rh];
        a10 = *(const float4*)&xaT[kp2][8 * rh + 4];
        FMA_BLOCK(a01, a11, wA1, wB1);
    }
#undef FMA_BLOCK

    // ---- split-K reduction: kh=1 waves dump, kh=0 waves add + write out ----
    __syncthreads();  // all xaT reads done; lds reusable
    if (kh == 1) {
        float* dst = &lds[rh * 4096];   // [16 slots][256 floats], float4/lane
#pragma unroll
        for (int a = 0; a < 2; ++a)
#pragma unroll
            for (int i = 0; i < 4; ++i) {
                *(float4*)&dst[(a * 4 + i) * 256 + lane * 4]     = accA[a][i];
                *(float4*)&dst[(8 + a * 4 + i) * 256 + lane * 4] = accB[a][i];
            }
    }
    __syncthreads();
    if (kh == 0) {
        const float* src = &lds[rh * 4096];
#pragma unroll
        for (int a = 0; a < 2; ++a)
#pragma unroll
            for (int i = 0; i < 4; ++i) {
                float4 pA = *(const float4*)&src[(a * 4 + i) * 256 + lane * 4];
                float4 pB = *(const float4*)&src[(8 + a * 4 + i) * 256 + lane * 4];
                accA[a][i].x += pA.x; accA[a][i].y += pA.y;
                accA[a][i].z += pA.z; accA[a][i].w += pA.w;
                accB[a][i].x += pB.x; accB[a][i].y += pB.y;
                accB[a][i].z += pB.z; accB[a][i].w += pB.w;
            }
        const float* lb = br ? si_lb : so_lb;
        float4 lbA = *(const float4*)&lb[col0];
        float4 lbB = *(const float4*)&lb[col0 + 256];
        float* lg = logits + ((size_t)br * 4096 + n0) * 1024;
#pragma unroll
        for (int a = 0; a < 2; ++a)
#pragma unroll
            for (int ri = 0; ri < 4; ++ri) {
                int row = 8 * rh + 4 * a + ri;
                float4 vA, vB;
                vA.x = (&accA[a][0].x)[ri] + lbA.x;
                vA.y = (&accA[a][1].x)[ri] + lbA.y;
                vA.z = (&accA[a][2].x)[ri] + lbA.z;
                vA.w = (&accA[a][3].x)[ri] + lbA.w;
                vB.x = (&accB[a][0].x)[ri] + lbB.x;
                vB.y = (&accB[a][1].x)[ri] + lbB.y;
                vB.z = (&accB[a][2].x)[ri] + lbB.z;
                vB.w = (&accB[a][3].x)[ri] + lbB.w;
                *(float4*)&lg[(size_t)row * 1024 + col0]       = vA;
                *(float4*)&lg[(size_t)row * 1024 + col0 + 256] = vB;
            }
    }
}

// ---------------- softmax stats + exact top-32 per row-branch ----------------
// One wave per row-branch. 3-level radix-histogram select on the orderable key
// (8 bits/level, 24 bits total), then a tiny serial argmax over the boundary
// set with full 64-bit (key, ~idx) ordering -> selected SET exactly matches
// jax.lax.top_k (ties -> lowest index). Output order is arbitrary (consumer is
// order-invariant).
__global__ __launch_bounds__(256) void topk_k(const float* __restrict__ logits,
                                              unsigned int* __restrict__ tidx,
                                              float* __restrict__ tval) {
    __shared__ unsigned int hist[4][256];
    __shared__ unsigned int wcnt[4];
    int wave = threadIdx.x >> 6, lane = threadIdx.x & 63;
    int rb = blockIdx.x * 4 + wave;  // 0..8191
    unsigned int* h = hist[wave];

    const float4* lg = (const float4*)(logits + (size_t)rb * 1024);
    float v[16];
#pragma unroll
    for (int q = 0; q < 4; ++q) {
        float4 f = lg[q * 64 + lane];
        v[q * 4 + 0] = f.x; v[q * 4 + 1] = f.y;
        v[q * 4 + 2] = f.z; v[q * 4 + 3] = f.w;
    }
    // row max
    float rmax = v[0];
#pragma unroll
    for (int i = 1; i < 16; ++i) rmax = fmaxf(rmax, v[i]);
#pragma unroll
    for (int s = 32; s; s >>= 1) rmax = fmaxf(rmax, __shfl_xor(rmax, s));
    // softmax denominator
    float rsum = 0.f;
#pragma unroll
    for (int i = 0; i < 16; ++i) rsum += __expf(v[i] - rmax);
#pragma unroll
    for (int s = 32; s; s >>= 1) rsum += __shfl_xor(rsum, s);

    unsigned int kb[16];
#pragma unroll
    for (int i = 0; i < 16; ++i) kb[i] = ford(v[i]);

    // --- 3-level radix descent: find 24-bit prefix of the 32nd-largest key ---
    unsigned inmask = 0xFFFFu;  // elements still in the boundary subset
    unsigned need = 32, prefix = 0, lasth = 0;
#pragma unroll
    for (int level = 0; level < 3; ++level) {
        int shift = 24 - level * 8;
        ((uint4*)h)[lane] = make_uint4(0u, 0u, 0u, 0u);
        __syncthreads();
#pragma unroll
        for (int i = 0; i < 16; ++i)
            if ((inmask >> i) & 1u) atomicAdd(&h[(kb[i] >> shift) & 0xFFu], 1u);
        __syncthreads();
        uint4 hv = ((const uint4*)h)[lane];  // bins 4*lane .. 4*lane+3
        unsigned sl = hv.x + hv.y + hv.z + hv.w;
        unsigned S = sl;  // suffix-inclusive scan: sum over lanes >= lane
#pragma unroll
        for (int off = 1; off < 64; off <<= 1) {
            unsigned o = __shfl_down(S, off);
            if (lane + off < 64) S += o;
        }
        unsigned above = S - sl;  // sum over lanes > lane
        unsigned cg3 = above + hv.w;
        unsigned cg2 = cg3 + hv.z;
        unsigned cg1 = cg2 + hv.y;
        unsigned cg0 = cg1 + hv.x;
        // local best bin = highest b in this lane with cnt_ge(b) >= need
        unsigned pack = 0;
        if      (cg3 >= need) pack = ((4u * lane + 3u) << 12) | cg3;
        else if (cg2 >= need) pack = ((4u * lane + 2u) << 12) | cg2;
        else if (cg1 >= need) pack = ((4u * lane + 1u) << 12) | cg1;
        else if (cg0 >= need) pack = ((4u * lane + 0u) << 12) | cg0;
#pragma unroll
        for (int s = 32; s; s >>= 1) {
            unsigned o = __shfl_xor(pack, s);
            pack = o > pack ? o : pack;
        }
        unsigned bstar = pack >> 12, cstar = pack & 0xFFFu;
        unsigned hstar = h[bstar];       // broadcast read
        need -= (cstar - hstar);         // strictly-above-bucket winners
        prefix = (prefix << 8) | bstar;
        lasth = hstar;
        unsigned nm = 0;
#pragma unroll
        for (int i = 0; i < 16; ++i)
            if (((inmask >> i) & 1u) && ((kb[i] >> shift) & 0xFFu) == bstar)
                nm |= 1u << i;
        inmask = nm;
        __syncthreads();  // protect h[] reads vs next level's zeroing
    }

    // --- boundary set: elements with (kb >> 8) == prefix, count == lasth -----
    unsigned winmask = 0;
    if (lasth == need) {
        winmask = inmask;  // whole boundary set wins
    } else {
        // serial top-`need` with full 64-bit (key, ~idx) ordering
        unsigned avail = inmask;
        unsigned long long best = 0ULL;
#pragma unroll
        for (int i = 0; i < 16; ++i)
            if ((avail >> i) & 1u) {
                int j = (i >> 2) * 256 + lane * 4 + (i & 3);
                unsigned long long k64 =
                    ((unsigned long long)kb[i] << 32) | (unsigned int)(~j);
                best = k64 > best ? k64 : best;
            }
        for (unsigned k = 0; k < need; ++k) {
            unsigned long long w = best;
#pragma unroll
            for (int s = 32; s; s >>= 1) {
                unsigned long long o = __shfl_xor(w, s);
                if (o > w) w = o;
            }
            if (best == w) {  // unique winner lane (keys globally unique)
                unsigned long long nb = 0ULL;
#pragma unroll
                for (int i = 0; i < 16; ++i)
                    if ((avail >> i) & 1u) {
                        int j = (i >> 2) * 256 + lane * 4 + (i & 3);
                        unsigned long long k64 =
                            ((unsigned long long)kb[i] << 32) | (unsigned int)(~j);
                        if (k64 == w) { winmask |= 1u << i; avail &= ~(1u << i); }
                        else nb = k64 > nb ? k64 : nb;
                    }
                best = nb;
            }
        }
    }

    // --- emit the 32 winners (arbitrary order; consumer is order-invariant) --
    if (lane == 0) wcnt[wave] = 0;
#pragma unroll
    for (int i = 0; i < 16; ++i) {
        bool wn = ((kb[i] >> 8) > prefix) || ((winmask >> i) & 1u);
        if (wn) {
            unsigned slot = atomicAdd(&wcnt[wave], 1u);
            int j = (i >> 2) * 256 + lane * 4 + (i & 3);
            tidx[(size_t)rb * 32 + slot] = (unsigned int)j;
            tval[(size_t)rb * 32 + slot] = __expf(v[i] - rmax) / rsum;
        }
    }
}

// ---------------- final: out = scatter(sov * x.wT[soi]) + sum_k siv_k*x_c*W[c,:] + bias
__global__ __launch_bounds__(256) void final_k(
    const float* __restrict__ x, const float* __restrict__ W,
    const float* __restrict__ wT, const float* __restrict__ bias,
    const unsigned int* __restrict__ tidx, const float* __restrict__ tval,
    float* __restrict__ out) {
    int n = blockIdx.x, t = threadIdx.x, wave = t >> 6, lane = t & 63;
    __shared__ float xr[1024];
    __shared__ float dres[32];
    __shared__ unsigned int gidx[32]; __shared__ float gval[32];
    __shared__ unsigned int iidx[32]; __shared__ float ival[32];

    ((float4*)xr)[t] = ((const float4*)(x + (size_t)n * 1024))[t];
    if (t < 32) {
        gidx[t] = tidx[(size_t)n * 32 + t];
        gval[t] = tval[(size_t)n * 32 + t];
    } else if (t < 64) {
        int k = t - 32;
        iidx[k] = tidx[((size_t)4096 + n) * 32 + k];
        ival[k] = tval[((size_t)4096 + n) * 32 + k];
    }
    __syncthreads();  // B1

    if (t < 32) ival[t] *= xr[iidx[t]];  // g_k = s_v_in * x[c_k]

    // out-branch: 32 gathered dot products, 8 per wave
    const float4* xr4 = (const float4*)xr;
#pragma unroll
    for (int d8 = 0; d8 < 8; ++d8) {
        int d = wave * 8 + d8;
        const float4* wrow = (const float4*)(wT + (size_t)gidx[d] * 1024);
        float s = 0.f;
#pragma unroll
        for (int q = 0; q < 4; ++q) {
            float4 a = wrow[q * 64 + lane];
            float4 b = xr4[q * 64 + lane];
            s += a.x * b.x + a.y * b.y + a.z * b.z + a.w * b.w;
        }
#pragma unroll
        for (int sft = 32; sft; sft >>= 1) s += __shfl_xor(s, sft);
        if (lane == 0) dres[d] = s * gval[d];
    }
    __syncthreads();  // B2: ival final, dres written, xr reads done

    // in-branch + bias (registers)
    float4 acc = ((const float4*)bias)[t];
    for (int k = 0; k < 32; ++k) {
        float g = ival[k];
        unsigned int c = iidx[k];
        float4 wr = ((const float4*)(W + (size_t)c * 1024))[t];
        acc.x = fmaf(g, wr.x, acc.x); acc.y = fmaf(g, wr.y, acc.y);
        acc.z = fmaf(g, wr.z, acc.z); acc.w = fmaf(g, wr.w, acc.w);
    }
    ((float4*)xr)[t] = acc;  // reuse xr as output row
    __syncthreads();  // B3
    if (t < 32) xr[gidx[t]] += dres[t];  // unique indices, no race
    __syncthreads();  // B4
    ((float4*)(out + (size_t)n * 1024))[t] = ((float4*)xr)[t];
}

extern "C" void kernel_launch(void* const* d_in, const int* in_sizes, int n_in,
                              void* d_out, int out_size, void* d_ws, size_t ws_size,
                              hipStream_t stream) {
    const float* x        = (const float*)d_in[0];
    const float* W        = (const float*)d_in[1];
    const float* bias     = (const float*)d_in[2];
    const float* so_cw    = (const float*)d_in[3];
    const float* so_cb    = (const float*)d_in[4];
    const float* so_gm    = (const float*)d_in[5];
    const float* so_bt    = (const float*)d_in[6];
    const float* so_lw    = (const float*)d_in[7];
    const float* so_lb    = (const float*)d_in[8];
    const float* si_cw    = (const float*)d_in[9];
    const float* si_cb    = (const float*)d_in[10];
    const float* si_gm    = (const float*)d_in[11];
    const float* si_bt    = (const float*)d_in[12];
    const float* si_lw    = (const float*)d_in[13];
    const float* si_lb    = (const float*)d_in[14];
    float* out = (float*)d_out;

    float* ws       = (float*)d_ws;
    float* wT       = ws;                       // 1048576
    float* linT     = ws + 1048576;             // 2 x 262144
    float* xc       = ws + 1572864;             // 2 x 1048576
    float* partials = ws + 3670016;             // 262144
    float* sc       = ws + 3932160;             // 1024
    float* logits   = ws + 3933184;             // 8388608
    unsigned int* tidx = (unsigned int*)(ws + 12321792);  // 262144
    float* tval     = ws + 12583936;            // 262144

    transpose_k<<<dim3(32, 32), dim3(32, 8), 0, stream>>>(W, wT, 1024, 1024);
    transpose_k<<<dim3(8, 32), dim3(32, 8), 0, stream>>>(so_lw, linT, 1024, 256);
    transpose_k<<<dim3(8, 32), dim3(32, 8), 0, stream>>>(si_lw, linT + 262144, 1024, 256);
    conv_stats_k<<<256, 256, 0, stream>>>(x, so_cw, so_cb, si_cw, si_cb, xc, partials);
    stats_k<<<2, 256, 0, stream>>>(partials, so_gm, so_bt, si_gm, si_bt, sc);
    logits_k<<<dim3(256, 2, 2), 256, 0, stream>>>(xc, sc, linT, so_lb, si_lb, logits);
    topk_k<<<2048, 256, 0, stream>>>(logits, tidx, tval);
    final_k<<<4096, 256, 0, stream>>>(x, W, wT, bias, tidx, tval, out);
}